// Round 1
// 267.677 us; speedup vs baseline: 1.1342x; 1.1342x over previous
//
#include <hip/hip_runtime.h>
#include <math.h>

// B=8, C=64, H=W=256. conv_sigma: OC=32, VALID 3x3 -> 254x254 (bf16 MFMA).
// blur: stride 2, reflect pad 1, sigma/kern precomputed by sigma_kernel.
//
// ws layout (float index): acc[0,256) ; kern params [256,288) ; wtb bf16 @ float-ofs 512
//   wtb[tap][oc][ic] (9*32*64 ushorts = 36 KB), ic-contiguous for B-frags.

typedef __attribute__((ext_vector_type(8))) short s8v;   // 8 bf16
typedef __attribute__((ext_vector_type(4))) float f4v;   // 4 f32

static __device__ inline unsigned short f2bf(float f) {
    union { float f; unsigned int u; } v; v.f = f;
    unsigned int u = v.u;
    unsigned int r = u + 0x7FFFu + ((u >> 16) & 1u);
    return (unsigned short)(r >> 16);
}

// pack 2 f32 -> 2 bf16 (RNE) in one instruction; lo = a, hi = b
static __device__ inline unsigned int pk_bf16(float a, float b) {
    unsigned int r;
    asm("v_cvt_pk_bf16_f32 %0, %1, %2" : "=v"(r) : "v"(a), "v"(b));
    return r;
}

// ---------------- prep: zero acc + weights -> bf16 [tap][oc][ic] ----------------
__global__ void prep_kernel(const float* __restrict__ w, float* __restrict__ ws) {
    int i = blockIdx.x * blockDim.x + threadIdx.x;
    if (i < 256) ws[i] = 0.f;
    if (i < 9 * 32 * 64) {
        int ic  = i & 63;
        int oc  = (i >> 6) & 31;
        int tap = i >> 11;
        unsigned short* wtb = (unsigned short*)(ws + 512);
        wtb[i] = f2bf(w[oc * 576 + ic * 9 + tap]);
    }
}

// ---------------- conv 3x3 VALID (bf16 MFMA) + relu + spatial reduce ----------------
// grid (8 bx, 32 by, 8 b), block 256 = 4 waves. Block: 8 oy x 32 ox x 32 oc.
// LDS slab: 10 rows x 37 px x 64 ic bf16, [pixel][ic], XOR-swizzled 16B chunks:
//   chunk(ic>>3 ^ (p&7)), so ds_read_b128 A-frags are ~conflict-free, and with
//   row width 37 (odd*... 37 mod 8 = 5) the write-side p&7 sweeps all keys too.
__global__ __launch_bounds__(256, 3) void conv_mfma_kernel(
        const float* __restrict__ x, const unsigned short* __restrict__ wtb,
        float* __restrict__ acc_out) {
    __shared__ __align__(16) unsigned char sx[370 * 128];  // 47360 B
    __shared__ float sred[4][32];

    const int bx = blockIdx.x, by = blockIdx.y, b = blockIdx.z;
    const int ox0 = bx * 32, oy0 = by * 8;
    const int tid = threadIdx.x;
    const int lane = tid & 63, w = tid >> 6;
    const int m = lane & 15, q = lane >> 4;

    // ---- stage: 10 rows x 36 px (9 float4 chunks) x 64 ic, fp32->bf16 ----
    // item i -> ch = i%9 (fastest: coalesced), yy = (i/9)%10, r4 = i/90 (ic quad)
    // each item: 4 x global_load_dwordx4 (4 px of ic 4r4..4r4+3), 4 x ds_write_b64
    const float* xb = x + (size_t)b * 64 * 65536;
    for (int i = tid; i < 1440; i += 256) {
        int ch = i % 9;
        int t9 = i / 9;
        int yy = t9 % 10;
        int r4 = t9 / 10;
        int y  = oy0 + yy;
        int xc = ox0 + ch * 4;
        if (y < 256 && xc < 256) {   // skipped slots feed only masked outputs
            const float* src = xb + (size_t)(r4 << 2) * 65536 + y * 256 + xc;
            float4 v0 = *(const float4*)(src);
            float4 v1 = *(const float4*)(src + 65536);
            float4 v2 = *(const float4*)(src + 131072);
            float4 v3 = *(const float4*)(src + 196608);
            const float* a0 = (const float*)&v0;
            const float* a1 = (const float*)&v1;
            const float* a2 = (const float*)&v2;
            const float* a3 = (const float*)&v3;
            int p0 = yy * 37 + ch * 4;
#pragma unroll
            for (int j = 0; j < 4; ++j) {
                int p = p0 + j;
                unsigned int lo = pk_bf16(a0[j], a1[j]);   // ic 4r4, 4r4+1
                unsigned int hi = pk_bf16(a2[j], a3[j]);   // ic 4r4+2, 4r4+3
                int cw = (r4 >> 1) ^ (p & 7);
                *(uint2*)(sx + p * 128 + cw * 16 + (r4 & 1) * 8) = make_uint2(lo, hi);
            }
        }
    }
    __syncthreads();

    // ---- K-loop: fully unrolled 9 taps, B-frags streamed from L2 ----
    f4v acc[4][2];
#pragma unroll
    for (int mt = 0; mt < 4; ++mt)
#pragma unroll
        for (int nt = 0; nt < 2; ++nt) acc[mt][nt] = (f4v)0.f;

    int pb[4];
#pragma unroll
    for (int mt = 0; mt < 4; ++mt)
        pb[mt] = (2 * w + (mt >> 1)) * 37 + (mt & 1) * 16 + m;

    const unsigned short* wB = wtb + m * 64 + q * 8;

#pragma unroll
    for (int t = 0; t < 9; ++t) {
        const int off = (t / 3) * 37 + (t % 3);   // compile-time tap offset
        s8v b00 = *(const s8v*)(wB + t * 2048);          // kc0, oc m
        s8v b01 = *(const s8v*)(wB + t * 2048 + 1024);   // kc0, oc 16+m
        s8v b10 = *(const s8v*)(wB + t * 2048 + 32);     // kc1, oc m
        s8v b11 = *(const s8v*)(wB + t * 2048 + 1024 + 32);
#pragma unroll
        for (int kc = 0; kc < 2; ++kc) {
            s8v bb0 = kc ? b10 : b00;
            s8v bb1 = kc ? b11 : b01;
#pragma unroll
            for (int mt = 0; mt < 4; ++mt) {
                int p = pb[mt] + off;
                int quad = (kc * 4 + q) ^ (p & 7);
                s8v afr = *(const s8v*)(sx + p * 128 + quad * 16);
                acc[mt][0] = __builtin_amdgcn_mfma_f32_16x16x32_bf16(afr, bb0, acc[mt][0], 0, 0, 0);
                acc[mt][1] = __builtin_amdgcn_mfma_f32_16x16x32_bf16(afr, bb1, acc[mt][1], 0, 0, 0);
            }
        }
    }

    // ---- epilogue: relu + mask invalid pixels + reduce ----
    // D layout: col(oc) = lane&15, row(pixel-x) = (lane>>4)*4 + reg
    float s0 = 0.f, s1 = 0.f;
#pragma unroll
    for (int mt = 0; mt < 4; ++mt) {
        int oy = oy0 + 2 * w + (mt >> 1);
        int oxb = ox0 + (mt & 1) * 16 + q * 4;
#pragma unroll
        for (int reg = 0; reg < 4; ++reg) {
            bool val = (oxb + reg < 254) && (oy < 254);
            if (val) {
                s0 += fmaxf(acc[mt][0][reg], 0.f);
                s1 += fmaxf(acc[mt][1][reg], 0.f);
            }
        }
    }
    s0 += __shfl_xor(s0, 16, 64); s0 += __shfl_xor(s0, 32, 64);
    s1 += __shfl_xor(s1, 16, 64); s1 += __shfl_xor(s1, 32, 64);
    if (lane < 16) { sred[w][lane] = s0; sred[w][16 + lane] = s1; }
    __syncthreads();
    if (tid < 32)
        atomicAdd(&acc_out[b * 32 + tid],
                  sred[0][tid] + sred[1][tid] + sred[2][tid] + sred[3][tid]);
}

// ---------------- sigma tail: fc + sigmoid + gaussian taps, once per batch ----------------
// 1 block x 64 threads: 8 lanes per b reduce the 32-wide fc dot.
__global__ void sigma_kernel(const float* __restrict__ acc, const float* __restrict__ wfc,
                             const float* __restrict__ bfc, float* __restrict__ kout) {
    int t = threadIdx.x;
    int b = t >> 3, j = t & 7;
    float s = 0.f;
#pragma unroll
    for (int i = 0; i < 4; ++i) s += acc[b * 32 + j + i * 8] * wfc[j + i * 8];
    s += __shfl_xor(s, 4, 8);
    s += __shfl_xor(s, 2, 8);
    s += __shfl_xor(s, 1, 8);
    if (j == 0) {
        float z = s * (1.0f / (254.0f * 254.0f)) + bfc[0];
        float sig = 1.0f / (1.0f + __expf(-z));
        float ss = fmaxf(sig, 1e-4f);
        float inv2 = 0.5f / (ss * ss);
        float e1 = __expf(-inv2);
        float e2 = __expf(-2.0f * inv2);
        float inv_norm = 1.0f / (1.0f + 4.0f * e1 + 4.0f * e2);
        kout[b * 4 + 0] = inv_norm;           // center
        kout[b * 4 + 1] = e1 * inv_norm;      // edge
        kout[b * 4 + 2] = e2 * inv_norm;      // diagonal
    }
}

// ---------------- blur: stride-2 3x3 with precomputed taps ----------------
// grid (16 oy-blocks, 8 b, 64 c), block 256 = 32 x-threads x 8 oy.
__global__ __launch_bounds__(256) void blur_kernel(
        const float* __restrict__ x, const float* __restrict__ kp,
        float* __restrict__ out) {
    const int c = blockIdx.z, b = blockIdx.y;
    const int tid = threadIdx.x;
    const int qx = tid & 31;                 // 4-output group
    const int oy = blockIdx.x * 8 + (tid >> 5);

    const float kC = kp[b * 4 + 0];
    const float kE = kp[b * 4 + 1];
    const float kD = kp[b * 4 + 2];

    const float* xb = x + ((size_t)(b * 64 + c)) * 65536;

    float o0 = 0.f, o1 = 0.f, o2 = 0.f, o3 = 0.f;
#pragma unroll
    for (int dy = 0; dy < 3; ++dy) {
        int iy = 2 * oy + dy - 1;
        if (iy < 0) iy = 1;                   // reflect
        const float* row = xb + iy * 256;
        const float4 f0 = *(const float4*)(row + 8 * qx);
        const float4 f1 = *(const float4*)(row + 8 * qx + 4);
        float lf = __shfl_up(f1.w, 1, 64);    // left neighbor's last element
        const float sm1 = (qx == 0) ? f0.y : lf;   // reflect at x=-1 -> x=1
        const float ka = (dy == 1) ? kE : kD;
        const float kb = (dy == 1) ? kC : kE;
        const float kc2 = (dy == 1) ? kE : kD;
        o0 = fmaf(ka, sm1,  fmaf(kb, f0.x, fmaf(kc2, f0.y, o0)));
        o1 = fmaf(ka, f0.y, fmaf(kb, f0.z, fmaf(kc2, f0.w, o1)));
        o2 = fmaf(ka, f0.w, fmaf(kb, f1.x, fmaf(kc2, f1.y, o2)));
        o3 = fmaf(ka, f1.y, fmaf(kb, f1.z, fmaf(kc2, f1.w, o3)));
    }
    *(float4*)(out + (((size_t)c * 8 + b) * 128 + oy) * 128 + 4 * qx) =
        make_float4(o0, o1, o2, o3);
}

extern "C" void kernel_launch(void* const* d_in, const int* in_sizes, int n_in,
                              void* d_out, int out_size, void* d_ws, size_t ws_size,
                              hipStream_t stream) {
    const float* x       = (const float*)d_in[0];
    const float* w_sigma = (const float*)d_in[1];
    const float* w_fc    = (const float*)d_in[2];
    const float* b_fc    = (const float*)d_in[3];
    float* out = (float*)d_out;
    float* ws  = (float*)d_ws;
    const unsigned short* wtb = (const unsigned short*)(ws + 512);

    prep_kernel<<<72, 256, 0, stream>>>(w_sigma, ws);
    conv_mfma_kernel<<<dim3(8, 32, 8), 256, 0, stream>>>(x, wtb, ws);
    sigma_kernel<<<1, 64, 0, stream>>>(ws, w_fc, b_fc, ws + 256);
    blur_kernel<<<dim3(16, 8, 64), 256, 0, stream>>>(x, ws + 256, out);
}

// Round 2
// 255.628 us; speedup vs baseline: 1.1877x; 1.0471x over previous
//
#include <hip/hip_runtime.h>
#include <math.h>

// B=8, C=64, H=W=256. conv_sigma: OC=32, VALID 3x3 -> 254x254 (bf16 MFMA).
// blur: stride 2, reflect pad 1, sigma/kern precomputed by sigma_kernel.
//
// ws layout (float index): acc[0,256) ; kern params [256,288) ; wtb bf16 @ float-ofs 512
//   wtb[tap][oc][ic] (9*32*64 ushorts = 36 KB), ic-contiguous for B-frags.

typedef __attribute__((ext_vector_type(8))) short s8v;   // 8 bf16
typedef __attribute__((ext_vector_type(4))) float f4v;   // 4 f32

static __device__ inline unsigned short f2bf(float f) {
    union { float f; unsigned int u; } v; v.f = f;
    unsigned int u = v.u;
    unsigned int r = u + 0x7FFFu + ((u >> 16) & 1u);
    return (unsigned short)(r >> 16);
}

// pack 2 f32 -> 2 bf16 (RNE) in one instruction; lo = a, hi = b
static __device__ inline unsigned int pk_bf16(float a, float b) {
    unsigned int r;
    asm("v_cvt_pk_bf16_f32 %0, %1, %2" : "=v"(r) : "v"(a), "v"(b));
    return r;
}

// ---------------- prep: zero acc + weights -> bf16 [tap][oc][ic] ----------------
__global__ void prep_kernel(const float* __restrict__ w, float* __restrict__ ws) {
    int i = blockIdx.x * blockDim.x + threadIdx.x;
    if (i < 256) ws[i] = 0.f;
    if (i < 9 * 32 * 64) {
        int ic  = i & 63;
        int oc  = (i >> 6) & 31;
        int tap = i >> 11;
        unsigned short* wtb = (unsigned short*)(ws + 512);
        wtb[i] = f2bf(w[oc * 576 + ic * 9 + tap]);
    }
}

// ---------------- conv 3x3 VALID (bf16 MFMA) + relu + spatial reduce ----------------
// grid (8 bx, 32 by, 8 b), block 256 = 4 waves. Block: 8 oy x 32 ox x 32 oc.
// LDS slab: 10 rows x 37 px x 64 ic bf16, [pixel][ic], XOR-swizzled 16B chunks:
//   chunk slot = ic_oct ^ ((p>>1)&7). Key (p>>1)&7: write-side chunk starts are
//   4-aligned in p, so (p&7) gave only 2 slots/wave-group (5-way conflicts);
//   (p>>1)&7 gives 4 slots from the ch sweep. Read side: 2 lanes/quad = free.
__global__ __launch_bounds__(256, 3) void conv_mfma_kernel(
        const float* __restrict__ x, const unsigned short* __restrict__ wtb,
        float* __restrict__ acc_out) {
    __shared__ __align__(16) unsigned char sx[370 * 128];  // 47360 B
    __shared__ float sred[4][32];

    const int bx = blockIdx.x, by = blockIdx.y, b = blockIdx.z;
    const int ox0 = bx * 32, oy0 = by * 8;
    const int tid = threadIdx.x;
    const int lane = tid & 63, w = tid >> 6;
    const int m = lane & 15, q = lane >> 4;

    // ---- stage phase 1: issue ALL 24 global float4 loads back-to-back ----
    // item i -> ch = i%9 (fastest: coalesced), yy = (i/9)%10, r4 = i/90 (ic quad)
    // Addresses are clamped in-bounds; halo/overrun slots hold finite garbage that
    // only feeds epilogue-masked outputs. Writes are guarded (i<1440) so no LDS
    // corruption from the padded 6th iteration.
    const float* xb = x + (size_t)b * 64 * 65536;
    float4 va[6][4];
    int   pj[6];
    int   r4a[6];
    bool  vld[6];
#pragma unroll
    for (int k = 0; k < 6; ++k) {
        int i  = tid + k * 256;
        int ch = i % 9;
        int t9 = i / 9;
        int yy = t9 % 10;
        int r4 = t9 / 10;
        int y  = oy0 + yy;  if (y > 255) y = 255;
        int xc = ox0 + ch * 4;  if (xc > 252) xc = 252;
        const float* src = xb + (size_t)((r4 & 15) << 2) * 65536 + y * 256 + xc;
        va[k][0] = *(const float4*)(src);
        va[k][1] = *(const float4*)(src + 65536);
        va[k][2] = *(const float4*)(src + 131072);
        va[k][3] = *(const float4*)(src + 196608);
        pj[k]  = yy * 37 + ch * 4;
        r4a[k] = r4;
        vld[k] = (i < 1440);
    }

    // ---- B-frag prefetch for tap 0 (independent of LDS; hides under barrier) ----
    const unsigned short* wB = wtb + m * 64 + q * 8;
    s8v bc0 = *(const s8v*)(wB);               // kc0, oc m
    s8v bc1 = *(const s8v*)(wB + 1024);        // kc0, oc 16+m
    s8v bc2 = *(const s8v*)(wB + 32);          // kc1, oc m
    s8v bc3 = *(const s8v*)(wB + 1024 + 32);   // kc1, oc 16+m

    // ---- stage phase 2: convert + LDS write ----
#pragma unroll
    for (int k = 0; k < 6; ++k) {
        if (vld[k]) {
            int r4 = r4a[k];
            const float* a0 = (const float*)&va[k][0];
            const float* a1 = (const float*)&va[k][1];
            const float* a2 = (const float*)&va[k][2];
            const float* a3 = (const float*)&va[k][3];
#pragma unroll
            for (int j = 0; j < 4; ++j) {
                int p = pj[k] + j;
                unsigned int lo = pk_bf16(a0[j], a1[j]);   // ic 4r4, 4r4+1
                unsigned int hi = pk_bf16(a2[j], a3[j]);   // ic 4r4+2, 4r4+3
                int cw = (r4 >> 1) ^ ((p >> 1) & 7);
                *(uint2*)(sx + p * 128 + cw * 16 + (r4 & 1) * 8) = make_uint2(lo, hi);
            }
        }
    }
    __syncthreads();

    // ---- K-loop: fully unrolled 9 taps, B-frags 2-deep software pipelined ----
    f4v acc[4][2];
#pragma unroll
    for (int mt = 0; mt < 4; ++mt)
#pragma unroll
        for (int nt = 0; nt < 2; ++nt) acc[mt][nt] = (f4v)0.f;

    int pb[4];
#pragma unroll
    for (int mt = 0; mt < 4; ++mt)
        pb[mt] = (2 * w + (mt >> 1)) * 37 + (mt & 1) * 16 + m;

#pragma unroll
    for (int t = 0; t < 9; ++t) {
        const int off = (t / 3) * 37 + (t % 3);   // compile-time tap offset
        s8v bn0, bn1, bn2, bn3;
        if (t < 8) {                               // compile-time branch
            const unsigned short* wN = wB + (t + 1) * 2048;
            bn0 = *(const s8v*)(wN);
            bn1 = *(const s8v*)(wN + 1024);
            bn2 = *(const s8v*)(wN + 32);
            bn3 = *(const s8v*)(wN + 1024 + 32);
        }
#pragma unroll
        for (int mt = 0; mt < 4; ++mt) {
            int p  = pb[mt] + off;
            int q0 = q ^ ((p >> 1) & 7);
            s8v afr = *(const s8v*)(sx + p * 128 + q0 * 16);
            acc[mt][0] = __builtin_amdgcn_mfma_f32_16x16x32_bf16(afr, bc0, acc[mt][0], 0, 0, 0);
            acc[mt][1] = __builtin_amdgcn_mfma_f32_16x16x32_bf16(afr, bc1, acc[mt][1], 0, 0, 0);
        }
#pragma unroll
        for (int mt = 0; mt < 4; ++mt) {
            int p  = pb[mt] + off;
            int q1 = (4 + q) ^ ((p >> 1) & 7);
            s8v afr = *(const s8v*)(sx + p * 128 + q1 * 16);
            acc[mt][0] = __builtin_amdgcn_mfma_f32_16x16x32_bf16(afr, bc2, acc[mt][0], 0, 0, 0);
            acc[mt][1] = __builtin_amdgcn_mfma_f32_16x16x32_bf16(afr, bc3, acc[mt][1], 0, 0, 0);
        }
        if (t < 8) { bc0 = bn0; bc1 = bn1; bc2 = bn2; bc3 = bn3; }
    }

    // ---- epilogue: relu + mask invalid pixels + reduce ----
    // D layout: col(oc) = lane&15, row(pixel-x) = (lane>>4)*4 + reg
    float s0 = 0.f, s1 = 0.f;
#pragma unroll
    for (int mt = 0; mt < 4; ++mt) {
        int oy = oy0 + 2 * w + (mt >> 1);
        int oxb = ox0 + (mt & 1) * 16 + q * 4;
#pragma unroll
        for (int reg = 0; reg < 4; ++reg) {
            bool val = (oxb + reg < 254) && (oy < 254);
            if (val) {
                s0 += fmaxf(acc[mt][0][reg], 0.f);
                s1 += fmaxf(acc[mt][1][reg], 0.f);
            }
        }
    }
    s0 += __shfl_xor(s0, 16, 64); s0 += __shfl_xor(s0, 32, 64);
    s1 += __shfl_xor(s1, 16, 64); s1 += __shfl_xor(s1, 32, 64);
    if (lane < 16) { sred[w][lane] = s0; sred[w][16 + lane] = s1; }
    __syncthreads();
    if (tid < 32)
        atomicAdd(&acc_out[b * 32 + tid],
                  sred[0][tid] + sred[1][tid] + sred[2][tid] + sred[3][tid]);
}

// ---------------- sigma tail: fc + sigmoid + gaussian taps, once per batch ----------------
// 1 block x 64 threads: 8 lanes per b reduce the 32-wide fc dot.
__global__ void sigma_kernel(const float* __restrict__ acc, const float* __restrict__ wfc,
                             const float* __restrict__ bfc, float* __restrict__ kout) {
    int t = threadIdx.x;
    int b = t >> 3, j = t & 7;
    float s = 0.f;
#pragma unroll
    for (int i = 0; i < 4; ++i) s += acc[b * 32 + j + i * 8] * wfc[j + i * 8];
    s += __shfl_xor(s, 4, 8);
    s += __shfl_xor(s, 2, 8);
    s += __shfl_xor(s, 1, 8);
    if (j == 0) {
        float z = s * (1.0f / (254.0f * 254.0f)) + bfc[0];
        float sig = 1.0f / (1.0f + __expf(-z));
        float ss = fmaxf(sig, 1e-4f);
        float inv2 = 0.5f / (ss * ss);
        float e1 = __expf(-inv2);
        float e2 = __expf(-2.0f * inv2);
        float inv_norm = 1.0f / (1.0f + 4.0f * e1 + 4.0f * e2);
        kout[b * 4 + 0] = inv_norm;           // center
        kout[b * 4 + 1] = e1 * inv_norm;      // edge
        kout[b * 4 + 2] = e2 * inv_norm;      // diagonal
    }
}

// ---------------- blur: stride-2 3x3 with precomputed taps ----------------
// grid (16 oy-blocks, 8 b, 64 c), block 256 = 32 x-threads x 8 oy.
__global__ __launch_bounds__(256) void blur_kernel(
        const float* __restrict__ x, const float* __restrict__ kp,
        float* __restrict__ out) {
    const int c = blockIdx.z, b = blockIdx.y;
    const int tid = threadIdx.x;
    const int qx = tid & 31;                 // 4-output group
    const int oy = blockIdx.x * 8 + (tid >> 5);

    const float kC = kp[b * 4 + 0];
    const float kE = kp[b * 4 + 1];
    const float kD = kp[b * 4 + 2];

    const float* xb = x + ((size_t)(b * 64 + c)) * 65536;

    float o0 = 0.f, o1 = 0.f, o2 = 0.f, o3 = 0.f;
#pragma unroll
    for (int dy = 0; dy < 3; ++dy) {
        int iy = 2 * oy + dy - 1;
        if (iy < 0) iy = 1;                   // reflect
        const float* row = xb + iy * 256;
        const float4 f0 = *(const float4*)(row + 8 * qx);
        const float4 f1 = *(const float4*)(row + 8 * qx + 4);
        float lf = __shfl_up(f1.w, 1, 64);    // left neighbor's last element
        const float sm1 = (qx == 0) ? f0.y : lf;   // reflect at x=-1 -> x=1
        const float ka = (dy == 1) ? kE : kD;
        const float kb = (dy == 1) ? kC : kE;
        const float kc2 = (dy == 1) ? kE : kD;
        o0 = fmaf(ka, sm1,  fmaf(kb, f0.x, fmaf(kc2, f0.y, o0)));
        o1 = fmaf(ka, f0.y, fmaf(kb, f0.z, fmaf(kc2, f0.w, o1)));
        o2 = fmaf(ka, f0.w, fmaf(kb, f1.x, fmaf(kc2, f1.y, o2)));
        o3 = fmaf(ka, f1.y, fmaf(kb, f1.z, fmaf(kc2, f1.w, o3)));
    }
    *(float4*)(out + (((size_t)c * 8 + b) * 128 + oy) * 128 + 4 * qx) =
        make_float4(o0, o1, o2, o3);
}

extern "C" void kernel_launch(void* const* d_in, const int* in_sizes, int n_in,
                              void* d_out, int out_size, void* d_ws, size_t ws_size,
                              hipStream_t stream) {
    const float* x       = (const float*)d_in[0];
    const float* w_sigma = (const float*)d_in[1];
    const float* w_fc    = (const float*)d_in[2];
    const float* b_fc    = (const float*)d_in[3];
    float* out = (float*)d_out;
    float* ws  = (float*)d_ws;
    const unsigned short* wtb = (const unsigned short*)(ws + 512);

    prep_kernel<<<72, 256, 0, stream>>>(w_sigma, ws);
    conv_mfma_kernel<<<dim3(8, 32, 8), 256, 0, stream>>>(x, wtb, ws);
    sigma_kernel<<<1, 64, 0, stream>>>(ws, w_fc, b_fc, ws + 256);
    blur_kernel<<<dim3(16, 8, 64), 256, 0, stream>>>(x, ws + 256, out);
}